// Round 1
// baseline (251.964 us; speedup 1.0000x reference)
//
#include <hip/hip_runtime.h>
#include <hip/hip_bf16.h>

// GaborBasis: out[b,t,r] = window * cos(z·K[r] + phi[r]),
//   window = exp(-max(|z|^2+|mu_r|^2-2 z·mu_r,0)/(2 sigma_r^2)) normalized over r.
// Shapes: z [16384,256] fp32, mu/K [1024,256] fp32, log_sigma/phi [1024].
// Plan: fp16 hi/lo split (3-term) MFMA GEMMs for cross & phase, fused epilogue,
// per-block row-sum partials in ws, then a normalize pass.

typedef _Float16 f16x8 __attribute__((ext_vector_type(8)));
typedef float f32x4 __attribute__((ext_vector_type(4)));

#define M_DIM 16384
#define R_DIM 1024
#define D_DIM 256

// ---------------- prep: z_sq[16384], mu_sq[1024], inv2s2[1024] ----------------
__global__ void gabor_prep(const float* __restrict__ z, const float* __restrict__ mu,
                           const float* __restrict__ ls,
                           float* __restrict__ zsq, float* __restrict__ musq,
                           float* __restrict__ inv2s2) {
    const int lane = threadIdx.x & 63;
    const int wv = threadIdx.x >> 6;
    const int bid = blockIdx.x;
    if (bid < 4096) {
        const int row = bid * 4 + wv;                 // 0..16383
        float4 v = *(const float4*)(z + (size_t)row * 256 + lane * 4);
        float s = v.x * v.x + v.y * v.y + v.z * v.z + v.w * v.w;
#pragma unroll
        for (int sh = 1; sh < 64; sh <<= 1) s += __shfl_xor(s, sh, 64);
        if (lane == 0) zsq[row] = s;
    } else {
        const int row = (bid - 4096) * 4 + wv;        // 0..1023
        float4 v = *(const float4*)(mu + (size_t)row * 256 + lane * 4);
        float s = v.x * v.x + v.y * v.y + v.z * v.z + v.w * v.w;
#pragma unroll
        for (int sh = 1; sh < 64; sh <<= 1) s += __shfl_xor(s, sh, 64);
        if (lane == 0) {
            musq[row] = s;
            float e = expf(ls[row]);
            inv2s2[row] = 1.0f / (2.0f * (e * e + 1e-8f));
        }
    }
}

// convert 16 fp32 -> hi/lo fp16 and store into swizzled LDS row
__device__ __forceinline__ void cvt_store16(_Float16* __restrict__ sbase, int srow, int g0,
                                            const float* __restrict__ v) {
    const int swz = srow & 7;
    f16x8 hh0, hh1, hl0, hl1;
#pragma unroll
    for (int j = 0; j < 8; ++j) {
        float x = v[j];
        _Float16 h = (_Float16)x;
        hh0[j] = h; hl0[j] = (_Float16)(x - (float)h);
        float y = v[j + 8];
        _Float16 h2 = (_Float16)y;
        hh1[j] = h2; hl1[j] = (_Float16)(y - (float)h2);
    }
    _Float16* rp = sbase + srow * 64;
    *(f16x8*)(rp + (((g0    ) ^ swz) << 3)) = hh0;
    *(f16x8*)(rp + (((g0 + 1) ^ swz) << 3)) = hh1;
    *(f16x8*)(rp + (((g0 + 4) ^ swz) << 3)) = hl0;
    *(f16x8*)(rp + (((g0 + 5) ^ swz) << 3)) = hl1;
}

// ---------------- main: 128x128 tile, 4 waves (64x64 each), K-step 32 ----------------
__global__ __launch_bounds__(256, 2) void gabor_main(
    const float* __restrict__ z, const float* __restrict__ mu,
    const float* __restrict__ Kmat, const float* __restrict__ phi,
    const float* __restrict__ zsq, const float* __restrict__ musq,
    const float* __restrict__ inv2s2, float* __restrict__ out,
    float* __restrict__ partial) {
    __shared__ _Float16 sA[128 * 64];   // z tile:  [row][8 granules of 8 halves] hi(k)=pos k, lo(k)=pos 32+k
    __shared__ _Float16 sM[128 * 64];   // mu tile
    __shared__ _Float16 sK[128 * 64];   // K tile
    __shared__ float sZsq[128], sMusq[128], sInv[128], sPhi[128];
    __shared__ float sRow[2][128];

    const int tid = threadIdx.x;
    const int mb = blockIdx.x >> 3;
    const int nb = blockIdx.x & 7;
    const int rbase = mb * 128;
    const int cbase = nb * 128;

    if (tid < 128) {
        sZsq[tid] = zsq[rbase + tid];
        sMusq[tid] = musq[cbase + tid];
        sInv[tid] = inv2s2[cbase + tid];
        sPhi[tid] = phi[cbase + tid];
    }

    f32x4 accC[4][4], accP[4][4];
#pragma unroll
    for (int i = 0; i < 4; ++i)
#pragma unroll
        for (int j = 0; j < 4; ++j) {
            accC[i][j] = (f32x4){0.f, 0.f, 0.f, 0.f};
            accP[i][j] = (f32x4){0.f, 0.f, 0.f, 0.f};
        }

    const int srow = tid >> 1;          // 0..127
    const int kq = (tid & 1) << 4;      // 0 or 16
    const int g0 = kq >> 3;             // 0 or 2
    const float* zp = z   + (size_t)(rbase + srow) * 256 + kq;
    const float* mp = mu  + (size_t)(cbase + srow) * 256 + kq;
    const float* kp = Kmat + (size_t)(cbase + srow) * 256 + kq;

    const int lane = tid & 63;
    const int wv = tid >> 6;
    const int wr = wv >> 1, wc = wv & 1;
    const int lr = lane & 15, lg = lane >> 4;

    for (int ks = 0; ks < 8; ++ks) {
        const int k0 = ks * 32;
        float va[16], vb[16], vk2[16];
#pragma unroll
        for (int q = 0; q < 4; ++q) {
            *(float4*)&va[q * 4]  = *(const float4*)(zp + k0 + q * 4);
            *(float4*)&vb[q * 4]  = *(const float4*)(mp + k0 + q * 4);
            *(float4*)&vk2[q * 4] = *(const float4*)(kp + k0 + q * 4);
        }
        __syncthreads();              // previous step's LDS reads done
        cvt_store16(sA, srow, g0, va);
        cvt_store16(sM, srow, g0, vb);
        cvt_store16(sK, srow, g0, vk2);
        __syncthreads();              // tiles ready

        f16x8 aHi[4], aLo[4];
#pragma unroll
        for (int mf = 0; mf < 4; ++mf) {
            int row = wr * 64 + mf * 16 + lr;
            aHi[mf] = *(f16x8*)&sA[row * 64 + (((lg    ) ^ (row & 7)) << 3)];
            aLo[mf] = *(f16x8*)&sA[row * 64 + (((lg + 4) ^ (row & 7)) << 3)];
        }
#pragma unroll
        for (int nf = 0; nf < 4; ++nf) {
            int col = wc * 64 + nf * 16 + lr;
            int o_hi = col * 64 + (((lg    ) ^ (col & 7)) << 3);
            int o_lo = col * 64 + (((lg + 4) ^ (col & 7)) << 3);
            f16x8 bmH = *(f16x8*)&sM[o_hi];
            f16x8 bmL = *(f16x8*)&sM[o_lo];
            f16x8 bkH = *(f16x8*)&sK[o_hi];
            f16x8 bkL = *(f16x8*)&sK[o_lo];
#pragma unroll
            for (int mf = 0; mf < 4; ++mf) {
                accC[mf][nf] = __builtin_amdgcn_mfma_f32_16x16x32_f16(aHi[mf], bmH, accC[mf][nf], 0, 0, 0);
                accC[mf][nf] = __builtin_amdgcn_mfma_f32_16x16x32_f16(aHi[mf], bmL, accC[mf][nf], 0, 0, 0);
                accC[mf][nf] = __builtin_amdgcn_mfma_f32_16x16x32_f16(aLo[mf], bmH, accC[mf][nf], 0, 0, 0);
                accP[mf][nf] = __builtin_amdgcn_mfma_f32_16x16x32_f16(aHi[mf], bkH, accP[mf][nf], 0, 0, 0);
                accP[mf][nf] = __builtin_amdgcn_mfma_f32_16x16x32_f16(aHi[mf], bkL, accP[mf][nf], 0, 0, 0);
                accP[mf][nf] = __builtin_amdgcn_mfma_f32_16x16x32_f16(aLo[mf], bkH, accP[mf][nf], 0, 0, 0);
            }
        }
    }

    // epilogue: w = exp(-max(zsq+musq-2c,0)*inv2s2); out = w*cos(p+phi) (unnormalized)
    float rs[16];
#pragma unroll
    for (int i = 0; i < 16; ++i) rs[i] = 0.f;

#pragma unroll
    for (int mf = 0; mf < 4; ++mf) {
#pragma unroll
        for (int nf = 0; nf < 4; ++nf) {
            int coll = wc * 64 + nf * 16 + lr;
            float msq = sMusq[coll], i2s = sInv[coll], ph0 = sPhi[coll];
            f32x4 c = accC[mf][nf], p = accP[mf][nf];
#pragma unroll
            for (int rg = 0; rg < 4; ++rg) {
                int rowl = wr * 64 + mf * 16 + lg * 4 + rg;
                float dsq = fmaxf(sZsq[rowl] + msq - 2.0f * c[rg], 0.f);
                float w = expf(-dsq * i2s);
                float cs = cosf(p[rg] + ph0);
                out[(size_t)(rbase + rowl) * R_DIM + cbase + coll] = w * cs;
                rs[mf * 4 + rg] += w;
            }
        }
    }
    // reduce w over the 16-lane column groups -> per-row partial over this block's 128 cols
#pragma unroll
    for (int i = 0; i < 16; ++i) {
#pragma unroll
        for (int sh = 1; sh < 16; sh <<= 1) rs[i] += __shfl_xor(rs[i], sh, 64);
    }
    if (lr == 0) {
#pragma unroll
        for (int mf = 0; mf < 4; ++mf)
#pragma unroll
            for (int rg = 0; rg < 4; ++rg)
                sRow[wc][wr * 64 + mf * 16 + lg * 4 + rg] = rs[mf * 4 + rg];
    }
    __syncthreads();
    if (tid < 128) partial[(size_t)(rbase + tid) * 8 + nb] = sRow[0][tid] + sRow[1][tid];
}

// ---------------- normalize: out[row,:] *= 1/max(sum_r w, 1e-6) ----------------
__global__ void gabor_norm(float* __restrict__ out, const float* __restrict__ partial) {
    const int row = blockIdx.x;
    const int t = threadIdx.x;
    const float* pp = partial + (size_t)row * 8;
    float s = 0.f;
#pragma unroll
    for (int i = 0; i < 8; ++i) s += pp[i];
    const float inv = 1.0f / fmaxf(s, 1e-6f);
    float4* o = (float4*)(out + (size_t)row * R_DIM);
    float4 v = o[t];
    v.x *= inv; v.y *= inv; v.z *= inv; v.w *= inv;
    o[t] = v;
}

extern "C" void kernel_launch(void* const* d_in, const int* in_sizes, int n_in,
                              void* d_out, int out_size, void* d_ws, size_t ws_size,
                              hipStream_t stream) {
    const float* z    = (const float*)d_in[0];
    const float* mu   = (const float*)d_in[1];
    const float* Kmat = (const float*)d_in[2];
    const float* ls   = (const float*)d_in[3];
    const float* phi  = (const float*)d_in[4];
    float* out = (float*)d_out;
    float* ws = (float*)d_ws;
    float* zsq     = ws;                       // 16384
    float* musq    = ws + 16384;               // 1024
    float* i2s     = ws + 16384 + 1024;        // 1024
    float* partial = ws + 16384 + 2048;        // 16384*8

    hipLaunchKernelGGL(gabor_prep, dim3(4096 + 256), dim3(256), 0, stream,
                       z, mu, ls, zsq, musq, i2s);
    hipLaunchKernelGGL(gabor_main, dim3((M_DIM / 128) * (R_DIM / 128)), dim3(256), 0, stream,
                       z, mu, Kmat, phi, zsq, musq, i2s, out, partial);
    hipLaunchKernelGGL(gabor_norm, dim3(M_DIM), dim3(256), 0, stream, out, partial);
}

// Round 2
// 110.552 us; speedup vs baseline: 2.2791x; 2.2791x over previous
//
#include <hip/hip_runtime.h>
#include <hip/hip_bf16.h>

// GaborBasis: out[b,t,r] = window_norm * cos(z·K[r] + phi[r]),
//   window = exp(-max(|z|^2+|mu_r|^2-2 z·mu_r,0)/(2 sigma_r^2)), normalized over r.
// z [16384,256] fp32, mu/K [1024,256] fp32, log_sigma/phi [1024].
// fp16 hi/lo 3-term split MFMA for both GEMMs; fused exp/cos epilogue;
// per-block row-sum partials; separate normalize pass (out stays L3-hot).
// Round 2: 8 waves x (64x32) per 128x128 tile -> acc fits in 64 VGPRs (round 1
// spilled: 1.25 GB scratch writes). + reg prefetch of next K-tile, XCD swizzle.

typedef _Float16 f16x8 __attribute__((ext_vector_type(8)));
typedef float f32x4 __attribute__((ext_vector_type(4)));

#define M_DIM 16384
#define R_DIM 1024

// ---------------- prep: z_sq[16384], mu_sq[1024], inv2s2[1024] ----------------
__global__ void gabor_prep(const float* __restrict__ z, const float* __restrict__ mu,
                           const float* __restrict__ ls,
                           float* __restrict__ zsq, float* __restrict__ musq,
                           float* __restrict__ inv2s2) {
    const int lane = threadIdx.x & 63;
    const int wv = threadIdx.x >> 6;
    const int bid = blockIdx.x;
    if (bid < 4096) {
        const int row = bid * 4 + wv;                 // 0..16383
        float4 v = *(const float4*)(z + (size_t)row * 256 + lane * 4);
        float s = v.x * v.x + v.y * v.y + v.z * v.z + v.w * v.w;
#pragma unroll
        for (int sh = 1; sh < 64; sh <<= 1) s += __shfl_xor(s, sh, 64);
        if (lane == 0) zsq[row] = s;
    } else {
        const int row = (bid - 4096) * 4 + wv;        // 0..1023
        float4 v = *(const float4*)(mu + (size_t)row * 256 + lane * 4);
        float s = v.x * v.x + v.y * v.y + v.z * v.z + v.w * v.w;
#pragma unroll
        for (int sh = 1; sh < 64; sh <<= 1) s += __shfl_xor(s, sh, 64);
        if (lane == 0) {
            musq[row] = s;
            float e = expf(ls[row]);
            inv2s2[row] = 1.0f / (2.0f * (e * e + 1e-8f));
        }
    }
}

// convert 8 fp32 -> hi/lo fp16, store into swizzled LDS row (granule = 16B unit)
__device__ __forceinline__ void cvt_store8(_Float16* __restrict__ base, int srow, int part,
                                           const float* __restrict__ v) {
    const int swz = srow & 7;
    f16x8 hh, hl;
#pragma unroll
    for (int j = 0; j < 8; ++j) {
        float x = v[j];
        _Float16 h = (_Float16)x;
        hh[j] = h;
        hl[j] = (_Float16)(x - (float)h);
    }
    _Float16* rp = base + srow * 64;
    *(f16x8*)(rp + (((part    ) ^ swz) << 3)) = hh;   // hi at granules 0..3
    *(f16x8*)(rp + (((part + 4) ^ swz) << 3)) = hl;   // lo at granules 4..7
}

// ---------------- main: 128x128 tile, 8 waves (64x32 each), K-step 32 ----------------
__global__ __launch_bounds__(512, 2) void gabor_main(
    const float* __restrict__ z, const float* __restrict__ mu,
    const float* __restrict__ Kmat, const float* __restrict__ phi,
    const float* __restrict__ zsq, const float* __restrict__ musq,
    const float* __restrict__ inv2s2, float* __restrict__ out,
    float* __restrict__ partial) {
    __shared__ _Float16 sA[128 * 64];   // z tile: [row][granule 0..3 = hi(k), 4..7 = lo(k)], granule^= row&7
    __shared__ _Float16 sM[128 * 64];   // mu tile
    __shared__ _Float16 sK[128 * 64];   // K tile
    __shared__ float sZsq[128], sMusq[128], sInv[128], sPhi[128];
    __shared__ float sRow[4][128];

    const int tid = threadIdx.x;
    // XCD-chunked swizzle: blocks sharing the same z row-panel (mb) land on one XCD.
    const int bid = blockIdx.x;
    const int xcd = bid & 7;
    const int kk = bid >> 3;           // 0..127
    const int mb = xcd * 16 + (kk >> 3);  // 0..127
    const int nb = kk & 7;                // 0..7
    const int rbase = mb * 128;
    const int cbase = nb * 128;

    if (tid < 128) {
        sZsq[tid] = zsq[rbase + tid];
        sMusq[tid] = musq[cbase + tid];
        sInv[tid] = inv2s2[cbase + tid];
        sPhi[tid] = phi[cbase + tid];
    }

    f32x4 accC[4][2], accP[4][2];
#pragma unroll
    for (int i = 0; i < 4; ++i)
#pragma unroll
        for (int j = 0; j < 2; ++j) {
            accC[i][j] = (f32x4){0.f, 0.f, 0.f, 0.f};
            accP[i][j] = (f32x4){0.f, 0.f, 0.f, 0.f};
        }

    // staging map: each thread handles 8 floats of one row of the 128x32 K-tile
    const int srow = tid >> 2;          // 0..127
    const int part = tid & 3;           // 0..3 (k sub-chunk of 8)
    const float* zp = z    + (size_t)(rbase + srow) * 256 + part * 8;
    const float* mp = mu   + (size_t)(cbase + srow) * 256 + part * 8;
    const float* kp = Kmat + (size_t)(cbase + srow) * 256 + part * 8;

    const int lane = tid & 63;
    const int wv = tid >> 6;            // 0..7
    const int wr = wv >> 2;             // 0..1  (M half: 64 rows)
    const int wc = wv & 3;              // 0..3  (N quarter: 32 cols)
    const int lr = lane & 15, lg = lane >> 4;

    float va[8], vb[8], vk[8];
    // prologue: load K-tile 0 into regs
    *(float4*)&va[0] = *(const float4*)(zp);
    *(float4*)&va[4] = *(const float4*)(zp + 4);
    *(float4*)&vb[0] = *(const float4*)(mp);
    *(float4*)&vb[4] = *(const float4*)(mp + 4);
    *(float4*)&vk[0] = *(const float4*)(kp);
    *(float4*)&vk[4] = *(const float4*)(kp + 4);

    for (int ks = 0; ks < 8; ++ks) {
        // stage current tile (regs -> LDS)
        cvt_store8(sA, srow, part, va);
        cvt_store8(sM, srow, part, vb);
        cvt_store8(sK, srow, part, vk);
        __syncthreads();                 // tiles ready

        // issue next tile's global loads now; latency hides under MFMA
        if (ks < 7) {
            const int off = (ks + 1) * 32;
            *(float4*)&va[0] = *(const float4*)(zp + off);
            *(float4*)&va[4] = *(const float4*)(zp + off + 4);
            *(float4*)&vb[0] = *(const float4*)(mp + off);
            *(float4*)&vb[4] = *(const float4*)(mp + off + 4);
            *(float4*)&vk[0] = *(const float4*)(kp + off);
            *(float4*)&vk[4] = *(const float4*)(kp + off + 4);
        }

        f16x8 aH[4], aL[4];
#pragma unroll
        for (int mf = 0; mf < 4; ++mf) {
            const int row = wr * 64 + mf * 16 + lr;
            const int rb = row * 64, swz = row & 7;
            aH[mf] = *(f16x8*)&sA[rb + (((lg    ) ^ swz) << 3)];
            aL[mf] = *(f16x8*)&sA[rb + (((lg + 4) ^ swz) << 3)];
        }
#pragma unroll
        for (int nf = 0; nf < 2; ++nf) {
            const int col = wc * 32 + nf * 16 + lr;
            const int cb = col * 64, swz = col & 7;
            const int o_hi = cb + (((lg    ) ^ swz) << 3);
            const int o_lo = cb + (((lg + 4) ^ swz) << 3);
            f16x8 bmH = *(f16x8*)&sM[o_hi];
            f16x8 bmL = *(f16x8*)&sM[o_lo];
            f16x8 bkH = *(f16x8*)&sK[o_hi];
            f16x8 bkL = *(f16x8*)&sK[o_lo];
#pragma unroll
            for (int mf = 0; mf < 4; ++mf) {
                accC[mf][nf] = __builtin_amdgcn_mfma_f32_16x16x32_f16(aH[mf], bmH, accC[mf][nf], 0, 0, 0);
                accC[mf][nf] = __builtin_amdgcn_mfma_f32_16x16x32_f16(aH[mf], bmL, accC[mf][nf], 0, 0, 0);
                accC[mf][nf] = __builtin_amdgcn_mfma_f32_16x16x32_f16(aL[mf], bmH, accC[mf][nf], 0, 0, 0);
                accP[mf][nf] = __builtin_amdgcn_mfma_f32_16x16x32_f16(aH[mf], bkH, accP[mf][nf], 0, 0, 0);
                accP[mf][nf] = __builtin_amdgcn_mfma_f32_16x16x32_f16(aH[mf], bkL, accP[mf][nf], 0, 0, 0);
                accP[mf][nf] = __builtin_amdgcn_mfma_f32_16x16x32_f16(aL[mf], bkH, accP[mf][nf], 0, 0, 0);
            }
        }
        __syncthreads();                 // all LDS reads done before next overwrite
    }

    // epilogue: w = exp(-max(zsq+musq-2c,0)*inv2s2); out = w*cos(p+phi) (unnormalized)
    float rs[16];
#pragma unroll
    for (int i = 0; i < 16; ++i) rs[i] = 0.f;

#pragma unroll
    for (int mf = 0; mf < 4; ++mf) {
#pragma unroll
        for (int nf = 0; nf < 2; ++nf) {
            const int coll = wc * 32 + nf * 16 + lr;
            const float msq = sMusq[coll], i2s = sInv[coll], ph0 = sPhi[coll];
            f32x4 c = accC[mf][nf], p = accP[mf][nf];
#pragma unroll
            for (int rg = 0; rg < 4; ++rg) {
                const int rowl = wr * 64 + mf * 16 + lg * 4 + rg;
                float dsq = fmaxf(sZsq[rowl] + msq - 2.0f * c[rg], 0.f);
                float w = expf(-dsq * i2s);
                float cs = cosf(p[rg] + ph0);
                out[(size_t)(rbase + rowl) * R_DIM + cbase + coll] = w * cs;
                rs[mf * 4 + rg] += w;
            }
        }
    }
    // reduce w over the 16 lanes of each column group
#pragma unroll
    for (int i = 0; i < 16; ++i) {
#pragma unroll
        for (int sh = 1; sh < 16; sh <<= 1) rs[i] += __shfl_xor(rs[i], sh, 64);
    }
    if (lr == 0) {
#pragma unroll
        for (int mf = 0; mf < 4; ++mf)
#pragma unroll
            for (int rg = 0; rg < 4; ++rg)
                sRow[wc][wr * 64 + mf * 16 + lg * 4 + rg] = rs[mf * 4 + rg];
    }
    __syncthreads();
    if (tid < 128)
        partial[(size_t)(rbase + tid) * 8 + nb] =
            sRow[0][tid] + sRow[1][tid] + sRow[2][tid] + sRow[3][tid];
}

// ---------------- normalize: out[row,:] *= 1/max(sum_r w, 1e-6) ----------------
__global__ void gabor_norm(float* __restrict__ out, const float* __restrict__ partial) {
    const int row = blockIdx.x;
    const int t = threadIdx.x;
    const float* pp = partial + (size_t)row * 8;
    float s = 0.f;
#pragma unroll
    for (int i = 0; i < 8; ++i) s += pp[i];
    const float inv = 1.0f / fmaxf(s, 1e-6f);
    float4* o = (float4*)(out + (size_t)row * R_DIM);
    float4 v = o[t];
    v.x *= inv; v.y *= inv; v.z *= inv; v.w *= inv;
    o[t] = v;
}

extern "C" void kernel_launch(void* const* d_in, const int* in_sizes, int n_in,
                              void* d_out, int out_size, void* d_ws, size_t ws_size,
                              hipStream_t stream) {
    const float* z    = (const float*)d_in[0];
    const float* mu   = (const float*)d_in[1];
    const float* Kmat = (const float*)d_in[2];
    const float* ls   = (const float*)d_in[3];
    const float* phi  = (const float*)d_in[4];
    float* out = (float*)d_out;
    float* ws = (float*)d_ws;
    float* zsq     = ws;                       // 16384
    float* musq    = ws + 16384;               // 1024
    float* i2s     = ws + 16384 + 1024;        // 1024
    float* partial = ws + 16384 + 2048;        // 16384*8

    hipLaunchKernelGGL(gabor_prep, dim3(4096 + 256), dim3(256), 0, stream,
                       z, mu, ls, zsq, musq, i2s);
    hipLaunchKernelGGL(gabor_main, dim3((M_DIM / 128) * (R_DIM / 128)), dim3(512), 0, stream,
                       z, mu, Kmat, phi, zsq, musq, i2s, out, partial);
    hipLaunchKernelGGL(gabor_norm, dim3(M_DIM), dim3(256), 0, stream, out, partial);
}

// Round 3
// 104.739 us; speedup vs baseline: 2.4056x; 1.0555x over previous
//
#include <hip/hip_runtime.h>

// GaborBasis: out[b,t,r] = window_norm * cos(z·K[r] + phi[r]),
//   window = exp(-max(|z|^2+|mu_r|^2-2 z·mu_r,0)/(2 sigma_r^2)), normalized over r.
// z [16384,256] fp32, mu/K [1024,256] fp32, log_sigma/phi [1024].
// fp16 hi/lo 3-term split MFMA (16x16x32) for both GEMMs; fused fast-math
// epilogue; per-block row partials; separate normalize pass.
// Round 3: (a) hi/lo split precomputed once into ws (round 2: cvt VALU redone
// 8x-128x per tile dominated VALUBusy=39%); (b) epilogue expf/cosf -> __expf +
// fract+poly cos (~13 VALU vs ~40). Fallback to in-kernel cvt if ws too small.

typedef _Float16 f16x8 __attribute__((ext_vector_type(8)));
typedef float f32x4 __attribute__((ext_vector_type(4)));

#define M_DIM 16384
#define R_DIM 1024
#define INV2PI 0.15915494309189535f

// ---------------- prep: z_sq[16384], mu_sq[1024], inv2s2[1024], phirev[1024] ----------------
__global__ void gabor_prep(const float* __restrict__ z, const float* __restrict__ mu,
                           const float* __restrict__ ls, const float* __restrict__ phi,
                           float* __restrict__ zsq, float* __restrict__ musq,
                           float* __restrict__ inv2s2, float* __restrict__ phirev) {
    const int lane = threadIdx.x & 63;
    const int wv = threadIdx.x >> 6;
    const int bid = blockIdx.x;
    if (bid < 4096) {
        const int row = bid * 4 + wv;                 // 0..16383
        float4 v = *(const float4*)(z + (size_t)row * 256 + lane * 4);
        float s = v.x * v.x + v.y * v.y + v.z * v.z + v.w * v.w;
#pragma unroll
        for (int sh = 1; sh < 64; sh <<= 1) s += __shfl_xor(s, sh, 64);
        if (lane == 0) zsq[row] = s;
    } else {
        const int row = (bid - 4096) * 4 + wv;        // 0..1023
        float4 v = *(const float4*)(mu + (size_t)row * 256 + lane * 4);
        float s = v.x * v.x + v.y * v.y + v.z * v.z + v.w * v.w;
#pragma unroll
        for (int sh = 1; sh < 64; sh <<= 1) s += __shfl_xor(s, sh, 64);
        if (lane == 0) {
            musq[row] = s;
            float e = expf(ls[row]);
            inv2s2[row] = 1.0f / (2.0f * (e * e + 1e-8f));
            phirev[row] = phi[row] * INV2PI;
        }
    }
}

// ---------------- split: fp32 -> fp16 hi/lo, layout [(row*8+ks)*64]: halves 0..31 hi(k), 32..63 lo(k) ----------------
__global__ void gabor_split(const float* __restrict__ z, const float* __restrict__ mu,
                            const float* __restrict__ Kmat,
                            _Float16* __restrict__ zhl, _Float16* __restrict__ muhl,
                            _Float16* __restrict__ khl) {
    const int t = blockIdx.x * 256 + threadIdx.x;     // 0..147455
    const float* src;
    _Float16* dst;
    int u;
    if (t < 131072)      { u = t;          src = z;    dst = zhl; }
    else if (t < 139264) { u = t - 131072; src = mu;   dst = muhl; }
    else                 { u = t - 139264; src = Kmat; dst = khl; }
    const int row = u >> 3, ks = u & 7;
    const float* sp = src + (size_t)row * 256 + ks * 32;
    float v[32];
#pragma unroll
    for (int q = 0; q < 8; ++q) *(float4*)&v[q * 4] = *(const float4*)(sp + q * 4);
    f16x8 hi[4], lo[4];
#pragma unroll
    for (int g = 0; g < 4; ++g)
#pragma unroll
        for (int j = 0; j < 8; ++j) {
            float x = v[g * 8 + j];
            _Float16 h = (_Float16)x;
            hi[g][j] = h;
            lo[g][j] = (_Float16)(x - (float)h);
        }
    _Float16* d = dst + ((size_t)row * 8 + ks) * 64;
#pragma unroll
    for (int g = 0; g < 4; ++g) {
        *(f16x8*)(d + g * 8)      = hi[g];
        *(f16x8*)(d + 32 + g * 8) = lo[g];
    }
}

// ---------------- main: 128x128 tile, 8 waves (64x32 each), K-step 32 ----------------
template <bool PRE>
__global__ __launch_bounds__(512, 2) void gabor_main(
    const float* __restrict__ z, const float* __restrict__ mu,
    const float* __restrict__ Kmat,
    const _Float16* __restrict__ zhl, const _Float16* __restrict__ muhl,
    const _Float16* __restrict__ khl,
    const float* __restrict__ zsq, const float* __restrict__ musq,
    const float* __restrict__ inv2s2, const float* __restrict__ phirev,
    float* __restrict__ out, float* __restrict__ partial) {
    __shared__ _Float16 sA[128 * 64];   // [row][granule 0..3 = hi(k), 4..7 = lo(k)], granule ^= row&7
    __shared__ _Float16 sM[128 * 64];
    __shared__ _Float16 sK[128 * 64];
    __shared__ float sZsq[128], sMusq[128], sInv[128], sPrv[128];
    __shared__ float sRow[4][128];

    const int tid = threadIdx.x;
    const int bid = blockIdx.x;
    const int xcd = bid & 7;
    const int kk = bid >> 3;
    const int mb = xcd * 16 + (kk >> 3);
    const int nb = kk & 7;
    const int rbase = mb * 128;
    const int cbase = nb * 128;

    if (tid < 128) {
        sZsq[tid] = zsq[rbase + tid];
        sMusq[tid] = musq[cbase + tid];
        sInv[tid] = inv2s2[cbase + tid];
        sPrv[tid] = phirev[cbase + tid];
    }

    f32x4 accC[4][2], accP[4][2];
#pragma unroll
    for (int i = 0; i < 4; ++i)
#pragma unroll
        for (int j = 0; j < 2; ++j) {
            accC[i][j] = (f32x4){0.f, 0.f, 0.f, 0.f};
            accP[i][j] = (f32x4){0.f, 0.f, 0.f, 0.f};
        }

    const int srow = tid >> 2;          // 0..127
    const int part = tid & 3;           // k granule 0..3
    const int swz = srow & 7;

    // staging source pointers
    const _Float16* zp16 = zhl + (size_t)(rbase + srow) * 512 + part * 8;
    const _Float16* mp16 = muhl + (size_t)(cbase + srow) * 512 + part * 8;
    const _Float16* kp16 = khl + (size_t)(cbase + srow) * 512 + part * 8;
    const float* zp32 = z + (size_t)(rbase + srow) * 256 + part * 8;
    const float* mp32 = mu + (size_t)(cbase + srow) * 256 + part * 8;
    const float* kp32 = Kmat + (size_t)(cbase + srow) * 256 + part * 8;

    const int lane = tid & 63;
    const int wv = tid >> 6;
    const int wr = wv >> 2;             // 0..1
    const int wc = wv & 3;              // 0..3
    const int lr = lane & 15, lg = lane >> 4;

    f16x8 zh, zl, mh, ml, kh, kl;
    auto loadT = [&](int ksx) {
        if constexpr (PRE) {
            zh = *(const f16x8*)(zp16 + ksx * 64);
            zl = *(const f16x8*)(zp16 + ksx * 64 + 32);
            mh = *(const f16x8*)(mp16 + ksx * 64);
            ml = *(const f16x8*)(mp16 + ksx * 64 + 32);
            kh = *(const f16x8*)(kp16 + ksx * 64);
            kl = *(const f16x8*)(kp16 + ksx * 64 + 32);
        } else {
            float va[8], vb[8], vk[8];
            *(float4*)&va[0] = *(const float4*)(zp32 + ksx * 32);
            *(float4*)&va[4] = *(const float4*)(zp32 + ksx * 32 + 4);
            *(float4*)&vb[0] = *(const float4*)(mp32 + ksx * 32);
            *(float4*)&vb[4] = *(const float4*)(mp32 + ksx * 32 + 4);
            *(float4*)&vk[0] = *(const float4*)(kp32 + ksx * 32);
            *(float4*)&vk[4] = *(const float4*)(kp32 + ksx * 32 + 4);
#pragma unroll
            for (int j = 0; j < 8; ++j) {
                _Float16 h = (_Float16)va[j]; zh[j] = h; zl[j] = (_Float16)(va[j] - (float)h);
                h = (_Float16)vb[j]; mh[j] = h; ml[j] = (_Float16)(vb[j] - (float)h);
                h = (_Float16)vk[j]; kh[j] = h; kl[j] = (_Float16)(vk[j] - (float)h);
            }
        }
    };

    loadT(0);
    for (int ks = 0; ks < 8; ++ks) {
        // stage regs -> LDS (swizzled granules)
        {
            _Float16* rp = &sA[srow * 64];
            *(f16x8*)(rp + (((part    ) ^ swz) << 3)) = zh;
            *(f16x8*)(rp + (((part + 4) ^ swz) << 3)) = zl;
            rp = &sM[srow * 64];
            *(f16x8*)(rp + (((part    ) ^ swz) << 3)) = mh;
            *(f16x8*)(rp + (((part + 4) ^ swz) << 3)) = ml;
            rp = &sK[srow * 64];
            *(f16x8*)(rp + (((part    ) ^ swz) << 3)) = kh;
            *(f16x8*)(rp + (((part + 4) ^ swz) << 3)) = kl;
        }
        __syncthreads();                 // tiles ready

        if (ks < 7) loadT(ks + 1);       // prefetch next tile; hides global latency

        f16x8 aH[4], aL[4];
#pragma unroll
        for (int mf = 0; mf < 4; ++mf) {
            const int row = wr * 64 + mf * 16 + lr;
            const int rb = row * 64, sw = row & 7;
            aH[mf] = *(f16x8*)&sA[rb + (((lg    ) ^ sw) << 3)];
            aL[mf] = *(f16x8*)&sA[rb + (((lg + 4) ^ sw) << 3)];
        }
#pragma unroll
        for (int nf = 0; nf < 2; ++nf) {
            const int col = wc * 32 + nf * 16 + lr;
            const int cb = col * 64, sw = col & 7;
            const int o_hi = cb + (((lg    ) ^ sw) << 3);
            const int o_lo = cb + (((lg + 4) ^ sw) << 3);
            f16x8 bmH = *(f16x8*)&sM[o_hi];
            f16x8 bmL = *(f16x8*)&sM[o_lo];
            f16x8 bkH = *(f16x8*)&sK[o_hi];
            f16x8 bkL = *(f16x8*)&sK[o_lo];
#pragma unroll
            for (int mf = 0; mf < 4; ++mf) {
                accC[mf][nf] = __builtin_amdgcn_mfma_f32_16x16x32_f16(aH[mf], bmH, accC[mf][nf], 0, 0, 0);
                accC[mf][nf] = __builtin_amdgcn_mfma_f32_16x16x32_f16(aH[mf], bmL, accC[mf][nf], 0, 0, 0);
                accC[mf][nf] = __builtin_amdgcn_mfma_f32_16x16x32_f16(aL[mf], bmH, accC[mf][nf], 0, 0, 0);
                accP[mf][nf] = __builtin_amdgcn_mfma_f32_16x16x32_f16(aH[mf], bkH, accP[mf][nf], 0, 0, 0);
                accP[mf][nf] = __builtin_amdgcn_mfma_f32_16x16x32_f16(aH[mf], bkL, accP[mf][nf], 0, 0, 0);
                accP[mf][nf] = __builtin_amdgcn_mfma_f32_16x16x32_f16(aL[mf], bkH, accP[mf][nf], 0, 0, 0);
            }
        }
        __syncthreads();                 // LDS reads done before next overwrite
    }

    // epilogue: w = __expf(-dsq*inv2s2); cos via revolutions + fract + deg-8 poly in u^2
    float rs[16];
#pragma unroll
    for (int i = 0; i < 16; ++i) rs[i] = 0.f;

#pragma unroll
    for (int mf = 0; mf < 4; ++mf) {
#pragma unroll
        for (int nf = 0; nf < 2; ++nf) {
            const int coll = wc * 32 + nf * 16 + lr;
            const float msq = sMusq[coll], il2 = sInv[coll], prv = sPrv[coll];
            f32x4 c = accC[mf][nf], p = accP[mf][nf];
#pragma unroll
            for (int rg = 0; rg < 4; ++rg) {
                const int rowl = wr * 64 + mf * 16 + lg * 4 + rg;
                float dsq = fmaxf(sZsq[rowl] + msq - 2.0f * c[rg], 0.f);
                float w = __expf(-dsq * il2);
                // cos(phase), phase = p + phi: rev = p/2pi + phi/2pi; r = fract(rev); u = r-1/2;
                // cos(2*pi*r) = -cos(2*pi*u), |u|<=1/2, Taylor deg-8 in s=u^2 (err <= 1.4e-7)
                float ph = __builtin_fmaf(p[rg], INV2PI, prv);
                float r = ph - floorf(ph);
                float uu = r - 0.5f;
                float s = uu * uu;
                float cs = 0.28203f;
                cs = __builtin_fmaf(cs, s, -1.71437f);
                cs = __builtin_fmaf(cs, s, 7.90348f);
                cs = __builtin_fmaf(cs, s, -26.42626f);
                cs = __builtin_fmaf(cs, s, 60.24464f);
                cs = __builtin_fmaf(cs, s, -85.45681720669371f);
                cs = __builtin_fmaf(cs, s, 64.93939402266829f);
                cs = __builtin_fmaf(cs, s, -19.739208802178716f);
                cs = __builtin_fmaf(cs, s, 1.0f);
                out[(size_t)(rbase + rowl) * R_DIM + cbase + coll] = -(w * cs);
                rs[mf * 4 + rg] += w;
            }
        }
    }
#pragma unroll
    for (int i = 0; i < 16; ++i) {
#pragma unroll
        for (int sh = 1; sh < 16; sh <<= 1) rs[i] += __shfl_xor(rs[i], sh, 64);
    }
    if (lr == 0) {
#pragma unroll
        for (int mf = 0; mf < 4; ++mf)
#pragma unroll
            for (int rg = 0; rg < 4; ++rg)
                sRow[wc][wr * 64 + mf * 16 + lg * 4 + rg] = rs[mf * 4 + rg];
    }
    __syncthreads();
    if (tid < 128)
        partial[(size_t)(rbase + tid) * 8 + nb] =
            sRow[0][tid] + sRow[1][tid] + sRow[2][tid] + sRow[3][tid];
}

// ---------------- normalize ----------------
__global__ void gabor_norm(float* __restrict__ out, const float* __restrict__ partial) {
    const int row = blockIdx.x;
    const int t = threadIdx.x;
    const float* pp = partial + (size_t)row * 8;
    float s = 0.f;
#pragma unroll
    for (int i = 0; i < 8; ++i) s += pp[i];
    const float inv = 1.0f / fmaxf(s, 1e-6f);
    float4* o = (float4*)(out + (size_t)row * R_DIM);
    float4 v = o[t];
    v.x *= inv; v.y *= inv; v.z *= inv; v.w *= inv;
    o[t] = v;
}

extern "C" void kernel_launch(void* const* d_in, const int* in_sizes, int n_in,
                              void* d_out, int out_size, void* d_ws, size_t ws_size,
                              hipStream_t stream) {
    const float* z    = (const float*)d_in[0];
    const float* mu   = (const float*)d_in[1];
    const float* Kmat = (const float*)d_in[2];
    const float* ls   = (const float*)d_in[3];
    const float* phi  = (const float*)d_in[4];
    float* out = (float*)d_out;
    float* ws = (float*)d_ws;
    float* zsq     = ws;                        // 16384
    float* musq    = ws + 16384;                // 1024
    float* i2s     = ws + 17408;                // 1024
    float* phirev  = ws + 18432;                // 1024
    float* partial = ws + 19456;                // 16384*8 -> ends at float 150528
    _Float16* zhl  = (_Float16*)(ws + 150528);  // 16384*512 halves
    _Float16* muhl = zhl + 8388608;             // 1024*512
    _Float16* khl  = muhl + 524288;             // 1024*512
    const bool pre = ws_size >= 19476480ull;    // 602112 B floats + 18.0 MiB halves

    hipLaunchKernelGGL(gabor_prep, dim3(4096 + 256), dim3(256), 0, stream,
                       z, mu, ls, phi, zsq, musq, i2s, phirev);
    if (pre) {
        hipLaunchKernelGGL(gabor_split, dim3(576), dim3(256), 0, stream,
                           z, mu, Kmat, zhl, muhl, khl);
        hipLaunchKernelGGL(gabor_main<true>, dim3((M_DIM / 128) * (R_DIM / 128)), dim3(512), 0, stream,
                           z, mu, Kmat, zhl, muhl, khl, zsq, musq, i2s, phirev, out, partial);
    } else {
        hipLaunchKernelGGL(gabor_main<false>, dim3((M_DIM / 128) * (R_DIM / 128)), dim3(512), 0, stream,
                           z, mu, Kmat, zhl, muhl, khl, zsq, musq, i2s, phirev, out, partial);
    }
    hipLaunchKernelGGL(gabor_norm, dim3(M_DIM), dim3(256), 0, stream, out, partial);
}

// Round 4
// 101.438 us; speedup vs baseline: 2.4839x; 1.0325x over previous
//
#include <hip/hip_runtime.h>

// GaborBasis: out[b,t,r] = window_norm * cos(z·K[r] + phi[r]),
//   window = exp(-max(|z|^2+|mu_r|^2-2 z·mu_r,0)/(2 sigma_r^2)), normalized over r.
// fp16 hi/lo 3-term split MFMA (16x16x32) for both GEMMs; fast-math epilogue.
// Round 4: (a) fragment-ordered hi/lo in ws -> LDS writes/reads are lane-linear
// (round 3: 3.15M bank conflicts from broken XOR swizzle = 8-way); (b) 64x64
// per-wave tile (block 128x256): 96 MFMA per 24 ds_read_b128 per K-step.

typedef _Float16 f16x8 __attribute__((ext_vector_type(8)));
typedef float f32x4 __attribute__((ext_vector_type(4)));

#define M_DIM 16384
#define R_DIM 1024
#define INV2PI 0.15915494309189535f

// ---------------- prep: z_sq[16384], mu_sq[1024], inv2s2[1024], phirev[1024] ----------------
__global__ void gabor_prep(const float* __restrict__ z, const float* __restrict__ mu,
                           const float* __restrict__ ls, const float* __restrict__ phi,
                           float* __restrict__ zsq, float* __restrict__ musq,
                           float* __restrict__ inv2s2, float* __restrict__ phirev) {
    const int lane = threadIdx.x & 63;
    const int wv = threadIdx.x >> 6;
    const int bid = blockIdx.x;
    if (bid < 4096) {
        const int row = bid * 4 + wv;
        float4 v = *(const float4*)(z + (size_t)row * 256 + lane * 4);
        float s = v.x * v.x + v.y * v.y + v.z * v.z + v.w * v.w;
#pragma unroll
        for (int sh = 1; sh < 64; sh <<= 1) s += __shfl_xor(s, sh, 64);
        if (lane == 0) zsq[row] = s;
    } else {
        const int row = (bid - 4096) * 4 + wv;
        float4 v = *(const float4*)(mu + (size_t)row * 256 + lane * 4);
        float s = v.x * v.x + v.y * v.y + v.z * v.z + v.w * v.w;
#pragma unroll
        for (int sh = 1; sh < 64; sh <<= 1) s += __shfl_xor(s, sh, 64);
        if (lane == 0) {
            musq[row] = s;
            float e = expf(ls[row]);
            inv2s2[row] = 1.0f / (2.0f * (e * e + 1e-8f));
            phirev[row] = phi[row] * INV2PI;
        }
    }
}

// ---------------- split: fp32 -> fp16 hi/lo in MFMA-fragment order ----------------
// Layout per matrix: [sub = row/16][ks = k/32][1024 halves]: hi at lane*8, lo at 512+lane*8,
// where lane = (row&15) | ((k>>3 & 3)<<4). One thread = one (sub,ks,lane) = 8 fp32.
__global__ void gabor_split(const float* __restrict__ z, const float* __restrict__ mu,
                            const float* __restrict__ Kmat,
                            _Float16* __restrict__ zf, _Float16* __restrict__ muf,
                            _Float16* __restrict__ kf) {
    const int t = blockIdx.x * 256 + threadIdx.x;   // 0..589823
    const float* src; _Float16* dst; int item;
    if (t < 524288)      { item = t;          src = z;    dst = zf; }
    else if (t < 557056) { item = t - 524288; src = mu;   dst = muf; }
    else                 { item = t - 557056; src = Kmat; dst = kf; }
    const int sub = item >> 9, rem = item & 511;
    const int ks = rem >> 6, l = rem & 63;
    const int row = sub * 16 + (l & 15);
    const int k0 = ks * 32 + (l >> 4) * 8;
    const float* sp = src + (size_t)row * 256 + k0;
    float v[8];
    *(float4*)&v[0] = *(const float4*)(sp);
    *(float4*)&v[4] = *(const float4*)(sp + 4);
    f16x8 hi, lo;
#pragma unroll
    for (int j = 0; j < 8; ++j) {
        _Float16 h = (_Float16)v[j];
        hi[j] = h;
        lo[j] = (_Float16)(v[j] - (float)h);
    }
    _Float16* d = dst + (size_t)(sub * 8 + ks) * 1024;
    *(f16x8*)(d + l * 8) = hi;
    *(f16x8*)(d + 512 + l * 8) = lo;
}

// ---------------- main: 128x256 tile, 8 waves (64x64 each), K-step 32 ----------------
template <bool PRE>
__global__ __launch_bounds__(512, 2) void gabor_main(
    const float* __restrict__ z, const float* __restrict__ mu, const float* __restrict__ Kmat,
    const _Float16* __restrict__ zf, const _Float16* __restrict__ muf, const _Float16* __restrict__ kf,
    const float* __restrict__ zsq, const float* __restrict__ musq,
    const float* __restrict__ inv2s2, const float* __restrict__ phirev,
    float* __restrict__ out, float* __restrict__ partial) {
    __shared__ _Float16 sA[8192];    // [sub 0..7][lane*8] hi; lo at +4096
    __shared__ _Float16 sM[16384];   // [sub 0..15][lane*8] hi; lo at +8192
    __shared__ _Float16 sK[16384];
    __shared__ float sZsq[128], sMusq[256], sInv[256], sPrv[256];
    __shared__ float sRow[4][128];

    const int tid = threadIdx.x;
    const int bid = blockIdx.x;
    const int xcd = bid & 7, kk = bid >> 3;      // kk 0..63
    const int mb = xcd * 16 + (kk >> 2);         // 0..127 (16 row-panels per XCD -> L2 reuse)
    const int nb = kk & 3;                        // 0..3
    const int rbase = mb * 128, cbase = nb * 256;

    if (tid < 256) {
        sMusq[tid] = musq[cbase + tid];
        sInv[tid] = inv2s2[cbase + tid];
        sPrv[tid] = phirev[cbase + tid];
    } else if (tid < 384) {
        sZsq[tid - 256] = zsq[rbase + tid - 256];
    }

    f32x4 accC[4][4], accP[4][4];
#pragma unroll
    for (int i = 0; i < 4; ++i)
#pragma unroll
        for (int j = 0; j < 4; ++j) {
            accC[i][j] = (f32x4){0.f, 0.f, 0.f, 0.f};
            accP[i][j] = (f32x4){0.f, 0.f, 0.f, 0.f};
        }

    // staging maps (all LDS writes lane-linear: A at tid*8, B at tid*16(+8))
    const int sA_s = tid >> 6, sA_l = tid & 63;
    const int sB_s = tid >> 5, sB_l = (tid & 31) * 2;

    const _Float16* zsrc = zf + (size_t)(mb * 8 + sA_s) * 8192 + sA_l * 8;
    const _Float16* msrc = muf + (size_t)(nb * 16 + sB_s) * 8192 + sB_l * 8;
    const _Float16* ksrc = kf + (size_t)(nb * 16 + sB_s) * 8192 + sB_l * 8;

    const int lane = tid & 63;
    const int wv = tid >> 6;
    const int wr = wv >> 2;            // 0..1
    const int wc = wv & 3;             // 0..3
    const int lr = lane & 15, lg = lane >> 4;

    f16x8 ra[2], rm[4], rk[4];
    auto loadT = [&](int ks) {
        if constexpr (PRE) {
            const _Float16* zp = zsrc + ks * 1024;
            ra[0] = *(const f16x8*)(zp);
            ra[1] = *(const f16x8*)(zp + 512);
            const _Float16* mp = msrc + ks * 1024;
            rm[0] = *(const f16x8*)(mp);
            rm[1] = *(const f16x8*)(mp + 8);
            rm[2] = *(const f16x8*)(mp + 512);
            rm[3] = *(const f16x8*)(mp + 520);
            const _Float16* kp = ksrc + ks * 1024;
            rk[0] = *(const f16x8*)(kp);
            rk[1] = *(const f16x8*)(kp + 8);
            rk[2] = *(const f16x8*)(kp + 512);
            rk[3] = *(const f16x8*)(kp + 520);
        } else {
            {
                const int row = rbase + sA_s * 16 + (sA_l & 15);
                const int k0 = ks * 32 + (sA_l >> 4) * 8;
                const float* sp = z + (size_t)row * 256 + k0;
                float v[8];
                *(float4*)&v[0] = *(const float4*)(sp);
                *(float4*)&v[4] = *(const float4*)(sp + 4);
#pragma unroll
                for (int j = 0; j < 8; ++j) {
                    _Float16 h = (_Float16)v[j];
                    ra[0][j] = h; ra[1][j] = (_Float16)(v[j] - (float)h);
                }
            }
#pragma unroll
            for (int j = 0; j < 2; ++j) {
                const int l = sB_l + j;
                const int row = cbase + sB_s * 16 + (l & 15);
                const int k0 = ks * 32 + (l >> 4) * 8;
                const float* sp = mu + (size_t)row * 256 + k0;
                float v[8];
                *(float4*)&v[0] = *(const float4*)(sp);
                *(float4*)&v[4] = *(const float4*)(sp + 4);
#pragma unroll
                for (int q = 0; q < 8; ++q) {
                    _Float16 h = (_Float16)v[q];
                    rm[j][q] = h; rm[2 + j][q] = (_Float16)(v[q] - (float)h);
                }
                const float* sp2 = Kmat + (size_t)row * 256 + k0;
                *(float4*)&v[0] = *(const float4*)(sp2);
                *(float4*)&v[4] = *(const float4*)(sp2 + 4);
#pragma unroll
                for (int q = 0; q < 8; ++q) {
                    _Float16 h = (_Float16)v[q];
                    rk[j][q] = h; rk[2 + j][q] = (_Float16)(v[q] - (float)h);
                }
            }
        }
    };

    loadT(0);
    for (int ks = 0; ks < 8; ++ks) {
        // stage regs -> LDS (all addresses lane-linear: zero bank conflicts)
        *(f16x8*)&sA[tid * 8] = ra[0];
        *(f16x8*)&sA[4096 + tid * 8] = ra[1];
        *(f16x8*)&sM[tid * 16] = rm[0];
        *(f16x8*)&sM[tid * 16 + 8] = rm[1];
        *(f16x8*)&sM[8192 + tid * 16] = rm[2];
        *(f16x8*)&sM[8192 + tid * 16 + 8] = rm[3];
        *(f16x8*)&sK[tid * 16] = rk[0];
        *(f16x8*)&sK[tid * 16 + 8] = rk[1];
        *(f16x8*)&sK[8192 + tid * 16] = rk[2];
        *(f16x8*)&sK[8192 + tid * 16 + 8] = rk[3];
        __syncthreads();                 // tiles ready

        if (ks < 7) loadT(ks + 1);       // prefetch next K-tile; hides global latency

        f16x8 aH[4], aL[4];
#pragma unroll
        for (int mf = 0; mf < 4; ++mf) {
            const int sub = wr * 4 + mf;
            aH[mf] = *(const f16x8*)&sA[sub * 512 + lane * 8];
            aL[mf] = *(const f16x8*)&sA[4096 + sub * 512 + lane * 8];
        }
#pragma unroll
        for (int nf = 0; nf < 4; ++nf) {
            const int sub = wc * 4 + nf;
            f16x8 bmH = *(const f16x8*)&sM[sub * 512 + lane * 8];
            f16x8 bmL = *(const f16x8*)&sM[8192 + sub * 512 + lane * 8];
            f16x8 bkH = *(const f16x8*)&sK[sub * 512 + lane * 8];
            f16x8 bkL = *(const f16x8*)&sK[8192 + sub * 512 + lane * 8];
#pragma unroll
            for (int mf = 0; mf < 4; ++mf) {
                accC[mf][nf] = __builtin_amdgcn_mfma_f32_16x16x32_f16(aH[mf], bmH, accC[mf][nf], 0, 0, 0);
                accC[mf][nf] = __builtin_amdgcn_mfma_f32_16x16x32_f16(aH[mf], bmL, accC[mf][nf], 0, 0, 0);
                accC[mf][nf] = __builtin_amdgcn_mfma_f32_16x16x32_f16(aL[mf], bmH, accC[mf][nf], 0, 0, 0);
                accP[mf][nf] = __builtin_amdgcn_mfma_f32_16x16x32_f16(aH[mf], bkH, accP[mf][nf], 0, 0, 0);
                accP[mf][nf] = __builtin_amdgcn_mfma_f32_16x16x32_f16(aH[mf], bkL, accP[mf][nf], 0, 0, 0);
                accP[mf][nf] = __builtin_amdgcn_mfma_f32_16x16x32_f16(aL[mf], bkH, accP[mf][nf], 0, 0, 0);
            }
        }
        __syncthreads();                 // LDS reads done before next overwrite
    }

    // epilogue: w = __expf(-dsq*inv2s2); cos via revolutions + fract + deg-8 poly
    float rs[16];
#pragma unroll
    for (int i = 0; i < 16; ++i) rs[i] = 0.f;

#pragma unroll
    for (int mf = 0; mf < 4; ++mf) {
#pragma unroll
        for (int nf = 0; nf < 4; ++nf) {
            const int cloc = wc * 64 + nf * 16 + lr;
            const float msq = sMusq[cloc], il2 = sInv[cloc], prv = sPrv[cloc];
            f32x4 c = accC[mf][nf], p = accP[mf][nf];
#pragma unroll
            for (int rg = 0; rg < 4; ++rg) {
                const int rowl = wr * 64 + mf * 16 + lg * 4 + rg;
                float dsq = fmaxf(sZsq[rowl] + msq - 2.0f * c[rg], 0.f);
                float w = __expf(-dsq * il2);
                float ph = __builtin_fmaf(p[rg], INV2PI, prv);
                float r = ph - floorf(ph);
                float uu = r - 0.5f;
                float s = uu * uu;
                float cs = 0.28203f;
                cs = __builtin_fmaf(cs, s, -1.71437f);
                cs = __builtin_fmaf(cs, s, 7.90348f);
                cs = __builtin_fmaf(cs, s, -26.42626f);
                cs = __builtin_fmaf(cs, s, 60.24464f);
                cs = __builtin_fmaf(cs, s, -85.45681720669371f);
                cs = __builtin_fmaf(cs, s, 64.93939402266829f);
                cs = __builtin_fmaf(cs, s, -19.739208802178716f);
                cs = __builtin_fmaf(cs, s, 1.0f);
                out[(size_t)(rbase + rowl) * R_DIM + cbase + cloc] = -(w * cs);
                rs[mf * 4 + rg] += w;
            }
        }
    }
#pragma unroll
    for (int i = 0; i < 16; ++i) {
#pragma unroll
        for (int sh = 1; sh < 16; sh <<= 1) rs[i] += __shfl_xor(rs[i], sh, 64);
    }
    if (lr == 0) {
#pragma unroll
        for (int mf = 0; mf < 4; ++mf)
#pragma unroll
            for (int rg = 0; rg < 4; ++rg)
                sRow[wc][wr * 64 + mf * 16 + lg * 4 + rg] = rs[mf * 4 + rg];
    }
    __syncthreads();
    if (tid < 128)
        partial[(size_t)(rbase + tid) * 4 + nb] =
            sRow[0][tid] + sRow[1][tid] + sRow[2][tid] + sRow[3][tid];
}

// ---------------- normalize ----------------
__global__ void gabor_norm(float* __restrict__ out, const float* __restrict__ partial) {
    const int row = blockIdx.x;
    const int t = threadIdx.x;
    const float* pp = partial + (size_t)row * 4;
    const float inv = 1.0f / fmaxf(pp[0] + pp[1] + pp[2] + pp[3], 1e-6f);
    float4* o = (float4*)(out + (size_t)row * R_DIM);
    float4 v = o[t];
    v.x *= inv; v.y *= inv; v.z *= inv; v.w *= inv;
    o[t] = v;
}

extern "C" void kernel_launch(void* const* d_in, const int* in_sizes, int n_in,
                              void* d_out, int out_size, void* d_ws, size_t ws_size,
                              hipStream_t stream) {
    const float* z    = (const float*)d_in[0];
    const float* mu   = (const float*)d_in[1];
    const float* Kmat = (const float*)d_in[2];
    const float* ls   = (const float*)d_in[3];
    const float* phi  = (const float*)d_in[4];
    float* out = (float*)d_out;
    float* ws = (float*)d_ws;
    float* zsq     = ws;                        // 16384
    float* musq    = ws + 16384;                // 1024
    float* i2s     = ws + 17408;                // 1024
    float* phirev  = ws + 18432;                // 1024
    float* partial = ws + 19456;                // 16384*4 -> ends at float 84992
    _Float16* zf  = (_Float16*)(ws + 84992);    // 16384*512 halves (fragment order)
    _Float16* muf = zf + 8388608;               // 1024*512
    _Float16* kf  = muf + 524288;               // 1024*512
    const bool pre = ws_size >= 19214336ull;

    hipLaunchKernelGGL(gabor_prep, dim3(4096 + 256), dim3(256), 0, stream,
                       z, mu, ls, phi, zsq, musq, i2s, phirev);
    if (pre) {
        hipLaunchKernelGGL(gabor_split, dim3(2304), dim3(256), 0, stream,
                           z, mu, Kmat, zf, muf, kf);
        hipLaunchKernelGGL(gabor_main<true>, dim3(512), dim3(512), 0, stream,
                           z, mu, Kmat, zf, muf, kf, zsq, musq, i2s, phirev, out, partial);
    } else {
        hipLaunchKernelGGL(gabor_main<false>, dim3(512), dim3(512), 0, stream,
                           z, mu, Kmat, zf, muf, kf, zsq, musq, i2s, phirev, out, partial);
    }
    hipLaunchKernelGGL(gabor_norm, dim3(M_DIM), dim3(256), 0, stream, out, partial);
}

// Round 5
// 99.300 us; speedup vs baseline: 2.5374x; 1.0215x over previous
//
#include <hip/hip_runtime.h>

// GaborBasis: out[b,t,r] = window_norm * cos(z·K[r] + phi[r]),
//   window = exp(-max(|z|^2+|mu_r|^2-2 z·mu_r,0)/(2 sigma_r^2)), normalized over r.
// fp16 hi/lo 3-term split MFMA (16x16x32); fast-math epilogue; norm pass.
// Round 5: B (mu,K) fragments load DIRECT from global (fragment-ordered ws,
// coalesced 1KB/wave, L2-hot) -- only A (z) staged in LDS, double-buffered.
// Round 4 lesson: 3-matrix LDS staging made LDS pipe co-critical (~25us) and
// 64x64 wave tile spilled (WRITE_SIZE +35MB). Back to 64x32 waves, acc=64 VGPR.

typedef _Float16 f16x8 __attribute__((ext_vector_type(8)));
typedef float f32x4 __attribute__((ext_vector_type(4)));

#define M_DIM 16384
#define R_DIM 1024
#define INV2PI 0.15915494309189535f

// ---------------- prep: z_sq[16384], mu_sq[1024], inv2s2[1024], phirev[1024] ----------------
__global__ void gabor_prep(const float* __restrict__ z, const float* __restrict__ mu,
                           const float* __restrict__ ls, const float* __restrict__ phi,
                           float* __restrict__ zsq, float* __restrict__ musq,
                           float* __restrict__ inv2s2, float* __restrict__ phirev) {
    const int lane = threadIdx.x & 63;
    const int wv = threadIdx.x >> 6;
    const int bid = blockIdx.x;
    if (bid < 4096) {
        const int row = bid * 4 + wv;
        float4 v = *(const float4*)(z + (size_t)row * 256 + lane * 4);
        float s = v.x * v.x + v.y * v.y + v.z * v.z + v.w * v.w;
#pragma unroll
        for (int sh = 1; sh < 64; sh <<= 1) s += __shfl_xor(s, sh, 64);
        if (lane == 0) zsq[row] = s;
    } else {
        const int row = (bid - 4096) * 4 + wv;
        float4 v = *(const float4*)(mu + (size_t)row * 256 + lane * 4);
        float s = v.x * v.x + v.y * v.y + v.z * v.z + v.w * v.w;
#pragma unroll
        for (int sh = 1; sh < 64; sh <<= 1) s += __shfl_xor(s, sh, 64);
        if (lane == 0) {
            musq[row] = s;
            float e = expf(ls[row]);
            inv2s2[row] = 1.0f / (2.0f * (e * e + 1e-8f));
            phirev[row] = phi[row] * INV2PI;
        }
    }
}

// ---------------- split: fp32 -> fp16 hi/lo in MFMA-fragment order ----------------
// Layout per matrix: [sub = row/16][ks = k/32][1024 halves]: hi at lane*8, lo at 512+lane*8,
// lane = (row&15) | ((k>>3 & 3)<<4). One thread = one (sub,ks,lane) = 8 fp32.
__global__ void gabor_split(const float* __restrict__ z, const float* __restrict__ mu,
                            const float* __restrict__ Kmat,
                            _Float16* __restrict__ zf, _Float16* __restrict__ muf,
                            _Float16* __restrict__ kf) {
    const int t = blockIdx.x * 256 + threadIdx.x;   // 0..589823
    const float* src; _Float16* dst; int item;
    if (t < 524288)      { item = t;          src = z;    dst = zf; }
    else if (t < 557056) { item = t - 524288; src = mu;   dst = muf; }
    else                 { item = t - 557056; src = Kmat; dst = kf; }
    const int sub = item >> 9, rem = item & 511;
    const int ks = rem >> 6, l = rem & 63;
    const int row = sub * 16 + (l & 15);
    const int k0 = ks * 32 + (l >> 4) * 8;
    const float* sp = src + (size_t)row * 256 + k0;
    float v[8];
    *(float4*)&v[0] = *(const float4*)(sp);
    *(float4*)&v[4] = *(const float4*)(sp + 4);
    f16x8 hi, lo;
#pragma unroll
    for (int j = 0; j < 8; ++j) {
        _Float16 h = (_Float16)v[j];
        hi[j] = h;
        lo[j] = (_Float16)(v[j] - (float)h);
    }
    _Float16* d = dst + (size_t)(sub * 8 + ks) * 1024;
    *(f16x8*)(d + l * 8) = hi;
    *(f16x8*)(d + 512 + l * 8) = lo;
}

// ---------------- main: 128x128 tile, 8 waves (64x32 each), K-step 32 ----------------
// A (z) staged in LDS double-buffered; B (mu,K) fragments direct from global.
template <bool PRE>
__global__ __launch_bounds__(512, 2) void gabor_main(
    const float* __restrict__ z, const float* __restrict__ mu, const float* __restrict__ Kmat,
    const _Float16* __restrict__ zf, const _Float16* __restrict__ muf, const _Float16* __restrict__ kf,
    const float* __restrict__ zsq, const float* __restrict__ musq,
    const float* __restrict__ inv2s2, const float* __restrict__ phirev,
    float* __restrict__ out, float* __restrict__ partial) {
    __shared__ _Float16 sA[2][8192];   // [buf][sub*512 + lane*8] hi; lo at +4096
    __shared__ float sZsq[128], sMusq[128], sInv[128], sPrv[128];
    __shared__ float sRow[4][128];

    const int tid = threadIdx.x;
    const int bid = blockIdx.x;
    const int xcd = bid & 7, kk = bid >> 3;   // kk 0..127
    const int mb = xcd * 16 + (kk >> 3);      // 0..127 (16 row-panels per XCD)
    const int nb = kk & 7;                    // 0..7
    const int rbase = mb * 128, cbase = nb * 128;

    if (tid < 128) {
        sZsq[tid] = zsq[rbase + tid];
        sMusq[tid] = musq[cbase + tid];
        sInv[tid] = inv2s2[cbase + tid];
        sPrv[tid] = phirev[cbase + tid];
    }

    f32x4 accC[4][2], accP[4][2];
#pragma unroll
    for (int i = 0; i < 4; ++i)
#pragma unroll
        for (int j = 0; j < 2; ++j) {
            accC[i][j] = (f32x4){0.f, 0.f, 0.f, 0.f};
            accP[i][j] = (f32x4){0.f, 0.f, 0.f, 0.f};
        }

    const int sub8 = tid >> 6, sl = tid & 63;
    const int lane = tid & 63;
    const int wv = tid >> 6;
    const int wr = wv >> 2;            // 0..1
    const int wc = wv & 3;             // 0..3
    const int lr = lane & 15, lg = lane >> 4;

    // A staging source (one fragment-row per thread)
    const _Float16* zsrc = zf + (size_t)((mb * 8 + sub8) * 8) * 1024 + sl * 8;
    // B fragment bases for this wave's 2 column-subs (16 cols each)
    const _Float16* mfp = muf + (size_t)((nb * 8 + wc * 2) * 8) * 1024 + lane * 8;
    const _Float16* kfp = kf  + (size_t)((nb * 8 + wc * 2) * 8) * 1024 + lane * 8;

    f16x8 raH, raL;
    auto loadA = [&](int ks) {
        if constexpr (PRE) {
            const _Float16* p = zsrc + ks * 1024;
            raH = *(const f16x8*)(p);
            raL = *(const f16x8*)(p + 512);
        } else {
            const int row = rbase + sub8 * 16 + (sl & 15);
            const float* sp = z + (size_t)row * 256 + ks * 32 + (sl >> 4) * 8;
            float v[8];
            *(float4*)&v[0] = *(const float4*)(sp);
            *(float4*)&v[4] = *(const float4*)(sp + 4);
#pragma unroll
            for (int j = 0; j < 8; ++j) {
                _Float16 h = (_Float16)v[j];
                raH[j] = h; raL[j] = (_Float16)(v[j] - (float)h);
            }
        }
    };

    loadA(0);
    *(f16x8*)&sA[0][sub8 * 512 + sl * 8] = raH;
    *(f16x8*)&sA[0][4096 + sub8 * 512 + sl * 8] = raL;
    __syncthreads();

    int b = 0;
    for (int ks = 0; ks < 8; ++ks) {
        if (ks < 7) loadA(ks + 1);     // next A tile global->regs; hides under MFMA

        f16x8 aH[4], aL[4];
#pragma unroll
        for (int mf = 0; mf < 4; ++mf) {
            const int o = (wr * 4 + mf) * 512 + lane * 8;
            aH[mf] = *(const f16x8*)&sA[b][o];
            aL[mf] = *(const f16x8*)&sA[b][4096 + o];
        }
#pragma unroll
        for (int nf = 0; nf < 2; ++nf) {
            f16x8 bmH, bmL, bkH, bkL;
            if constexpr (PRE) {
                const _Float16* mp = mfp + nf * 8192 + ks * 1024;
                bmH = *(const f16x8*)(mp);
                bmL = *(const f16x8*)(mp + 512);
                const _Float16* kp = kfp + nf * 8192 + ks * 1024;
                bkH = *(const f16x8*)(kp);
                bkL = *(const f16x8*)(kp + 512);
            } else {
                const int col = cbase + (wc * 2 + nf) * 16 + lr;
                const int k0 = ks * 32 + lg * 8;
                float v[8];
                const float* sp = mu + (size_t)col * 256 + k0;
                *(float4*)&v[0] = *(const float4*)(sp);
                *(float4*)&v[4] = *(const float4*)(sp + 4);
#pragma unroll
                for (int q = 0; q < 8; ++q) {
                    _Float16 h = (_Float16)v[q];
                    bmH[q] = h; bmL[q] = (_Float16)(v[q] - (float)h);
                }
                const float* sp2 = Kmat + (size_t)col * 256 + k0;
                *(float4*)&v[0] = *(const float4*)(sp2);
                *(float4*)&v[4] = *(const float4*)(sp2 + 4);
#pragma unroll
                for (int q = 0; q < 8; ++q) {
                    _Float16 h = (_Float16)v[q];
                    bkH[q] = h; bkL[q] = (_Float16)(v[q] - (float)h);
                }
            }
            __builtin_amdgcn_s_setprio(1);
#pragma unroll
            for (int mf = 0; mf < 4; ++mf) {
                accC[mf][nf] = __builtin_amdgcn_mfma_f32_16x16x32_f16(aH[mf], bmH, accC[mf][nf], 0, 0, 0);
                accC[mf][nf] = __builtin_amdgcn_mfma_f32_16x16x32_f16(aH[mf], bmL, accC[mf][nf], 0, 0, 0);
                accC[mf][nf] = __builtin_amdgcn_mfma_f32_16x16x32_f16(aL[mf], bmH, accC[mf][nf], 0, 0, 0);
                accP[mf][nf] = __builtin_amdgcn_mfma_f32_16x16x32_f16(aH[mf], bkH, accP[mf][nf], 0, 0, 0);
                accP[mf][nf] = __builtin_amdgcn_mfma_f32_16x16x32_f16(aH[mf], bkL, accP[mf][nf], 0, 0, 0);
                accP[mf][nf] = __builtin_amdgcn_mfma_f32_16x16x32_f16(aL[mf], bkH, accP[mf][nf], 0, 0, 0);
            }
            __builtin_amdgcn_s_setprio(0);
        }
        if (ks < 7) {
            *(f16x8*)&sA[b ^ 1][sub8 * 512 + sl * 8] = raH;
            *(f16x8*)&sA[b ^ 1][4096 + sub8 * 512 + sl * 8] = raL;
        }
        __syncthreads();
        b ^= 1;
    }

    // epilogue: w = __expf(-dsq*inv2s2); cos via revolutions + fract + deg-8 poly
    float rs[16];
#pragma unroll
    for (int i = 0; i < 16; ++i) rs[i] = 0.f;

#pragma unroll
    for (int mf = 0; mf < 4; ++mf) {
#pragma unroll
        for (int nf = 0; nf < 2; ++nf) {
            const int cloc = wc * 32 + nf * 16 + lr;
            const float msq = sMusq[cloc], il2 = sInv[cloc], prv = sPrv[cloc];
            f32x4 c = accC[mf][nf], p = accP[mf][nf];
#pragma unroll
            for (int rg = 0; rg < 4; ++rg) {
                const int rowl = wr * 64 + mf * 16 + lg * 4 + rg;
                float dsq = fmaxf(sZsq[rowl] + msq - 2.0f * c[rg], 0.f);
                float w = __expf(-dsq * il2);
                float ph = __builtin_fmaf(p[rg], INV2PI, prv);
                float r = ph - floorf(ph);
                float uu = r - 0.5f;
                float s = uu * uu;
                float cs = 0.28203f;
                cs = __builtin_fmaf(cs, s, -1.71437f);
                cs = __builtin_fmaf(cs, s, 7.90348f);
                cs = __builtin_fmaf(cs, s, -26.42626f);
                cs = __builtin_fmaf(cs, s, 60.24464f);
                cs = __builtin_fmaf(cs, s, -85.45681720669371f);
                cs = __builtin_fmaf(cs, s, 64.93939402266829f);
                cs = __builtin_fmaf(cs, s, -19.739208802178716f);
                cs = __builtin_fmaf(cs, s, 1.0f);
                out[(size_t)(rbase + rowl) * R_DIM + cbase + cloc] = -(w * cs);
                rs[mf * 4 + rg] += w;
            }
        }
    }
#pragma unroll
    for (int i = 0; i < 16; ++i) {
#pragma unroll
        for (int sh = 1; sh < 16; sh <<= 1) rs[i] += __shfl_xor(rs[i], sh, 64);
    }
    if (lr == 0) {
#pragma unroll
        for (int mf = 0; mf < 4; ++mf)
#pragma unroll
            for (int rg = 0; rg < 4; ++rg)
                sRow[wc][wr * 64 + mf * 16 + lg * 4 + rg] = rs[mf * 4 + rg];
    }
    __syncthreads();
    if (tid < 128)
        partial[(size_t)(rbase + tid) * 8 + nb] =
            sRow[0][tid] + sRow[1][tid] + sRow[2][tid] + sRow[3][tid];
}

// ---------------- normalize ----------------
__global__ void gabor_norm(float* __restrict__ out, const float* __restrict__ partial) {
    const int row = blockIdx.x;
    const int t = threadIdx.x;
    const float* pp = partial + (size_t)row * 8;
    float s = 0.f;
#pragma unroll
    for (int i = 0; i < 8; ++i) s += pp[i];
    const float inv = 1.0f / fmaxf(s, 1e-6f);
    float4* o = (float4*)(out + (size_t)row * R_DIM);
    float4 v = o[t];
    v.x *= inv; v.y *= inv; v.z *= inv; v.w *= inv;
    o[t] = v;
}

extern "C" void kernel_launch(void* const* d_in, const int* in_sizes, int n_in,
                              void* d_out, int out_size, void* d_ws, size_t ws_size,
                              hipStream_t stream) {
    const float* z    = (const float*)d_in[0];
    const float* mu   = (const float*)d_in[1];
    const float* Kmat = (const float*)d_in[2];
    const float* ls   = (const float*)d_in[3];
    const float* phi  = (const float*)d_in[4];
    float* out = (float*)d_out;
    float* ws = (float*)d_ws;
    float* zsq     = ws;                        // 16384
    float* musq    = ws + 16384;                // 1024
    float* i2s     = ws + 17408;                // 1024
    float* phirev  = ws + 18432;                // 1024
    float* partial = ws + 19456;                // 16384*8 -> ends at float 150528
    _Float16* zf  = (_Float16*)(ws + 150528);   // 16384*512 halves (fragment order)
    _Float16* muf = zf + 8388608;               // 1024*512
    _Float16* kf  = muf + 524288;               // 1024*512
    const bool pre = ws_size >= 19476480ull;

    hipLaunchKernelGGL(gabor_prep, dim3(4096 + 256), dim3(256), 0, stream,
                       z, mu, ls, phi, zsq, musq, i2s, phirev);
    if (pre) {
        hipLaunchKernelGGL(gabor_split, dim3(2304), dim3(256), 0, stream,
                           z, mu, Kmat, zf, muf, kf);
        hipLaunchKernelGGL(gabor_main<true>, dim3(1024), dim3(512), 0, stream,
                           z, mu, Kmat, zf, muf, kf, zsq, musq, i2s, phirev, out, partial);
    } else {
        hipLaunchKernelGGL(gabor_main<false>, dim3(1024), dim3(512), 0, stream,
                           z, mu, Kmat, zf, muf, kf, zsq, musq, i2s, phirev, out, partial);
    }
    hipLaunchKernelGGL(gabor_norm, dim3(M_DIM), dim3(256), 0, stream, out, partial);
}